// Round 8
// baseline (533.995 us; speedup 1.0000x reference)
//
#include <hip/hip_runtime.h>
#include <hip/hip_bf16.h>

// MHA forward: x[4,2048,1024] -> qkv GEMM -> flash attention (transposed
// S^T/O^T formulation, P stays in registers) -> out proj. bf16 MFMA 16x16x32.
//
// R8 changes (R7 post-mortem: VALU trims gave 0; flash is concurrency-bound
// at 8 waves/CU with all pipes <50%):
//  - flash: 8-wave blocks (512 thr), QBLK=256 (each wave keeps 32 q, same
//    per-wave registers ~124). 512 blocks x 50KB LDS -> 2 blocks/CU ->
//    16 waves/CU = 4 waves/SIMD (2x). K/V staging + barriers amortized 2x.
//  - __launch_bounds__(512,4) caps VGPR at 128 (natural ~116-124).
//  - single flash dispatch again (split was diagnostic; GEMMs < 79us each).
//  - keep: exp2-direct softmax, max3 tree, v_perm pack, l-sum via ones-MFMA,
//    mask zero-tile flags, Q pre-scale in GEMM, defer logic, setprio.

typedef __attribute__((ext_vector_type(8))) short short8;
typedef __attribute__((ext_vector_type(4))) float f32x4;

#define SCL2E 0.1803368801111204f  /* 0.125 * log2(e) */
#define L2E   1.44269504088896340736f

#define GLD16(g, l)                                                            \
  __builtin_amdgcn_global_load_lds(                                            \
      (const __attribute__((address_space(1))) unsigned int*)(g),              \
      (__attribute__((address_space(3))) unsigned int*)(l), 16, 0, 0)

__device__ __forceinline__ unsigned short f2b(float f) {
  union { float f; unsigned int u; } v; v.f = f;
  unsigned int u = v.u;
  return (unsigned short)((u + 0x7fffu + ((u >> 16) & 1u)) >> 16);
}
__device__ __forceinline__ unsigned int fbits(float f) {
  union { float f; unsigned int u; } v; v.f = f; return v.u;
}
__device__ __forceinline__ unsigned int cvt_pk_bf16(float lo, float hi) {
  unsigned int r;
  asm("v_cvt_pk_bf16_f32 %0, %1, %2" : "=v"(r) : "v"(lo), "v"(hi));
  return r;
}
__device__ __forceinline__ float max3f(float a, float b, float c) {
  return fmaxf(fmaxf(a, b), c);   // fuses to v_max3_f32
}

// ------- prep: fp32->bf16 convert (blocks 0..8191) + mask tile byte-flags
// (blocks 8192..8447; flag (qt,kt) nonzero -> mflagsB[qt*16+kt]=1). Each
// flag byte written by exactly one block with a plain store (no reset/race).
__global__ void prep(const float* __restrict__ in, ushort* __restrict__ out,
                     const float* __restrict__ mask,
                     unsigned char* __restrict__ mflagsB) {
  const int bid = blockIdx.x;
  if (bid < 8192) {
    int i = (bid * 256 + threadIdx.x) * 4;
    float4 f = *(const float4*)(in + i);
    ushort4 o;
    o.x = f2b(f.x); o.y = f2b(f.y); o.z = f2b(f.z); o.w = f2b(f.w);
    *(ushort4*)(out + i) = o;
    return;
  }
  __shared__ unsigned int s;
  const int t = bid - 8192;            // 0..255
  const int qt = t >> 4, kt = t & 15;
  const float* base = mask + (size_t)(qt * 128) * 2048 + kt * 128;
  const int row = threadIdx.x >> 1, col0 = (threadIdx.x & 1) * 64;
  unsigned int acc = 0;
#pragma unroll
  for (int i = 0; i < 16; ++i) {
    float4 f = *(const float4*)(base + (size_t)row * 2048 + col0 + i * 4);
    acc |= fbits(f.x) | fbits(f.y) | fbits(f.z) | fbits(f.w);
  }
  acc &= 0x7fffffffu;  // treat -0.0f as zero
  if (threadIdx.x == 0) s = 0u;
  __syncthreads();
  if (acc) atomicOr(&s, 1u);
  __syncthreads();
  if (threadIdx.x == 0) mflagsB[t] = s ? 1 : 0;
}

// -- both W[K][N] fp32 -> Wt[N][K] bf16 transposes in one launch (64x64) --
__global__ void transpose_cvt2(const float* __restrict__ W1, ushort* __restrict__ Wt1,
                               const float* __restrict__ W2, ushort* __restrict__ Wt2) {
  __shared__ float tile[64][65];
  const int bx = blockIdx.x;
  const float* W; ushort* Wt; int N, n0;
  if (bx < 48) { W = W1; Wt = Wt1; N = 3072; n0 = bx * 64; }
  else         { W = W2; Wt = Wt2; N = 1024; n0 = (bx - 48) * 64; }
  const int K = 1024, k0 = blockIdx.y * 64;
  int tx = threadIdx.x & 63, ty = threadIdx.x >> 6;  // ty 0..3
#pragma unroll
  for (int i = 0; i < 64; i += 4)
    tile[ty + i][tx] = W[(size_t)(k0 + ty + i) * N + n0 + tx];
  __syncthreads();
#pragma unroll
  for (int i = 0; i < 64; i += 4)
    Wt[(size_t)(n0 + ty + i) * K + k0 + tx] = f2b(tile[tx][ty + i]);
}

// ---------------- GEMM: C[M,N] = A[M,K] @ Bt[N,K]^T + bias ----------------
// QSCALE=1: multiply q-columns (col%192 < 64) by SCL2E after bias (f32,
// before bf16 rounding) so flash_attn's score prep needs no scaling.
template <int OUTF32, int QSCALE>
__global__ __launch_bounds__(256, 2) void gemm_bt_bias(
    const ushort* __restrict__ A, const ushort* __restrict__ Bt,
    const float* __restrict__ bias, void* __restrict__ Cout,
    int M, int N, int K) {
  __shared__ ushort As[128 * 64];
  __shared__ ushort Bs[128 * 64];
  const int lane = threadIdx.x & 63;
  const int wv = threadIdx.x >> 6;
  const int bm = blockIdx.y, bn = blockIdx.x;
  const int wm = wv >> 1, wn = wv & 1;
  f32x4 acc[4][4] = {};
  const size_t arow0 = (size_t)bm * 128;
  const size_t brow0 = (size_t)bn * 128;

  for (int k0 = 0; k0 < K; k0 += 64) {
    __syncthreads();
#pragma unroll
    for (int i = 0; i < 4; ++i) {
      int r = wv * 32 + i * 8 + (lane >> 3);
      const ushort* ga = A + (arow0 + r) * K + k0 + (lane & 7) * 8;
      GLD16(ga, As + (wv * 32 + i * 8) * 64);
      const ushort* gb = Bt + (brow0 + r) * K + k0 + (lane & 7) * 8;
      GLD16(gb, Bs + (wv * 32 + i * 8) * 64);
    }
    __syncthreads();
    short8 af[2][4], bf[2][4];
#pragma unroll
    for (int kf = 0; kf < 2; ++kf)
#pragma unroll
      for (int t = 0; t < 4; ++t) {
        af[kf][t] = *(const short8*)(As + (wm * 64 + t * 16 + (lane & 15)) * 64 +
                                     kf * 32 + (lane >> 4) * 8);
        bf[kf][t] = *(const short8*)(Bs + (wn * 64 + t * 16 + (lane & 15)) * 64 +
                                     kf * 32 + (lane >> 4) * 8);
      }
#pragma unroll
    for (int kf = 0; kf < 2; ++kf)
#pragma unroll
      for (int mt = 0; mt < 4; ++mt)
#pragma unroll
        for (int nt = 0; nt < 4; ++nt)
          acc[mt][nt] = __builtin_amdgcn_mfma_f32_16x16x32_bf16(
              af[kf][mt], bf[kf][nt], acc[mt][nt], 0, 0, 0);
  }
#pragma unroll
  for (int nt = 0; nt < 4; ++nt) {
    int col = bn * 128 + wn * 64 + nt * 16 + (lane & 15);
    float bv = bias[col];
    float scl = (QSCALE && (col % 192) < 64) ? SCL2E : 1.0f;
#pragma unroll
    for (int mt = 0; mt < 4; ++mt) {
      int row0 = bm * 128 + wm * 64 + mt * 16 + (lane >> 4) * 4;
#pragma unroll
      for (int r = 0; r < 4; ++r) {
        float v = acc[mt][nt][r] + bv;
        if (QSCALE) v *= scl;
        if (OUTF32)
          ((float*)Cout)[(size_t)(row0 + r) * N + col] = v;
        else
          ((ushort*)Cout)[(size_t)(row0 + r) * N + col] = f2b(v);
      }
    }
  }
}

// ---------------- flash attention (transposed formulation) ----------------
// qkv bf16 [8192, 3072]; head h: q cols [192h,192h+64) (PRE-SCALED by SCL2E),
// k +64, v +128. Block = (b,h, qtile of 256 rows): 8 waves, each wave owns
// 32 q (2 mt). bh-fast block order. S^T = K.Q^T -> softmax in-lane;
// O^T = V^T.P^T; l via ones-MFMA. exp2-direct fast path. Ks double-buffered
// (GLD16), Vt single-buffered (reg-staged). 2 blocks/CU -> 16 waves/CU.
__global__ __launch_bounds__(512, 4) void flash_attn(
    const ushort* __restrict__ qkv, const float* __restrict__ mask,
    const unsigned char* __restrict__ mflagsB,
    float* __restrict__ values_f, ushort* __restrict__ values_b) {
  __shared__ ushort Ks[2][128 * 64];   // swizzled rows, double-buffered
  __shared__ ushort Vt[64 * 136];      // V^T, permuted key-columns, stride 136

  const int lane = threadIdx.x & 63;
  const int wv = threadIdx.x >> 6;  // 0..7
  const int c = lane & 15;          // q within mt-tile
  const int g = lane >> 4;          // key quarter-group
  const int bh = blockIdx.x & 63;   // bh FAST: concurrent blocks share mask qt
  const int qt = blockIdx.x >> 6;   // 0..7 (tiles of 256 q)
  const int b = bh >> 4, h = bh & 15;
  const size_t rowbase = (size_t)b * 2048;
  const int qcol = h * 192;
  const int swz = (c & 3) << 1;     // read-side chunk xor for Ks

  unsigned int flbits = 0;
  {
    // wave wv covers q rows [qt*256 + wv*32, +32) -> mask tile qt*2 + (wv>>2)
    const unsigned char* mb = mflagsB + (qt * 2 + (wv >> 2)) * 16;
#pragma unroll
    for (int i = 0; i < 16; ++i) flbits |= (mb[i] ? 1u : 0u) << i;
  }

  // all-ones bf16 A-fragment (1.0 = 0x3F80) for the l-sum MFMA
  const short8 vone = {0x3F80, 0x3F80, 0x3F80, 0x3F80,
                       0x3F80, 0x3F80, 0x3F80, 0x3F80};

  // Q b-frags straight from global (pre-scaled by SCL2E in GEMM epilogue)
  short8 qf[2][2];
#pragma unroll
  for (int mt = 0; mt < 2; ++mt)
#pragma unroll
    for (int kf = 0; kf < 2; ++kf)
      qf[mt][kf] = *(const short8*)(qkv +
          (rowbase + qt * 256 + wv * 32 + mt * 16 + c) * 3072 + qcol +
          kf * 32 + g * 8);

  f32x4 acc[2][4] = {};
  f32x4 accl[2] = {};               // l-sum accumulator (all 4 rows identical)
  float mst[2] = {0.f, 0.f};        // exp2-direct: base offset, 0 = no offset

  // V staging mapping: thread -> key pair (K0,K0+1), d-eighth dq (8 d-elems)
  const int K0 = lane * 2;
  const int dq = wv;                 // 0..7
  const int pc0 = ((K0 >> 5) << 5) + (((K0 >> 2) & 3) << 3) +
                  (((K0 >> 4) & 1) << 2) + (K0 & 3);   // permuted column of K0
  const int vdw = pc0 >> 1;                            // dword column
  const int gcol = (((lane & 7) ^ (((lane >> 3) & 3) << 1)) << 3);

  short8 va0, vb0;                  // in-flight V regs for next tile

  auto loadV = [&](int t) {
    const ushort* vg = qkv + (rowbase + t * 128 + K0) * 3072 + qcol + 128 + dq * 8;
    va0 = *(const short8*)(vg);
    vb0 = *(const short8*)(vg + 3072);
  };
  auto writeV = [&]() {
    unsigned int* Vdw = (unsigned int*)Vt;
    const unsigned int* aw0 = (const unsigned int*)&va0;
    const unsigned int* bw0 = (const unsigned int*)&vb0;
#pragma unroll
    for (int k = 0; k < 4; ++k) {
      Vdw[(dq * 8 + 2 * k + 0) * 68 + vdw] =
          __builtin_amdgcn_perm(bw0[k], aw0[k], 0x05040100u);
      Vdw[(dq * 8 + 2 * k + 1) * 68 + vdw] =
          __builtin_amdgcn_perm(bw0[k], aw0[k], 0x07060302u);
    }
  };
  auto stageK = [&](int t, ushort* KsD) {
#pragma unroll
    for (int i = 0; i < 2; ++i) {
      int rloc = wv * 16 + i * 8;
      const ushort* gk = qkv + (rowbase + t * 128 + rloc + (lane >> 3)) * 3072 +
                         qcol + 64 + gcol;
      GLD16(gk, KsD + rloc * 64);
    }
  };

  const float* mrow = mask + (size_t)(qt * 256 + wv * 32 + c) * 2048 + g * 4;

  // ---- prologue: stage tile 0 ----
  loadV(0);
  stageK(0, Ks[0]);
  writeV();

  for (int kt = 0; kt < 16; ++kt) {
    __syncthreads();               // Ks[cur](kt) + Vt(kt) ready
    const int cur = kt & 1;
    const ushort* KsC = Ks[cur];
    // issue next tile's loads; latency hides under QK/softmax/PV below
    if (kt < 15) {
      loadV(kt + 1);
      stageK(kt + 1, Ks[cur ^ 1]);
    }

    const bool hasmask = (flbits >> kt) & 1u;
    const float* mkt = mrow + kt * 128;
    // mask for mt=0 issued early (overlaps QK MFMAs); skipped for zero tiles
    float4 msk0[8];
    if (hasmask) {
#pragma unroll
      for (int nt = 0; nt < 8; ++nt) msk0[nt] = *(const float4*)(mkt + nt * 16);
    }

    // ---- S^T = K . Q^T ----
    f32x4 sc[2][8];
    __builtin_amdgcn_s_setprio(1);
#pragma unroll
    for (int nt = 0; nt < 8; ++nt) {
      short8 k0 = *(const short8*)(KsC + (nt * 16 + c) * 64 + ((g ^ swz) << 3));
      short8 k1 = *(const short8*)(KsC + (nt * 16 + c) * 64 + (((4 + g) ^ swz) << 3));
      f32x4 z = {0.f, 0.f, 0.f, 0.f};
      sc[0][nt] = __builtin_amdgcn_mfma_f32_16x16x32_bf16(k0, qf[0][0], z, 0, 0, 0);
      sc[0][nt] = __builtin_amdgcn_mfma_f32_16x16x32_bf16(k1, qf[0][1], sc[0][nt], 0, 0, 0);
      sc[1][nt] = __builtin_amdgcn_mfma_f32_16x16x32_bf16(k0, qf[1][0], z, 0, 0, 0);
      sc[1][nt] = __builtin_amdgcn_mfma_f32_16x16x32_bf16(k1, qf[1][1], sc[1][nt], 0, 0, 0);
    }
    __builtin_amdgcn_s_setprio(0);

    // ---- online softmax (exp2-direct; in-lane keys) ----
    __attribute__((aligned(16))) unsigned int Dw[2][16];
#pragma unroll
    for (int mt = 0; mt < 2; ++mt) {
      f32x4 t4[8];
      if (hasmask) {
#pragma unroll
        for (int nt = 0; nt < 8; ++nt) {
          float4 mk = (mt == 0) ? msk0[nt]
                                : *(const float4*)(mkt + 16 * 2048 + nt * 16);
#pragma unroll
          for (int r = 0; r < 4; ++r)
            t4[nt][r] = fmaf(((const float*)&mk)[r], L2E, sc[mt][nt][r]);
        }
      } else {
#pragma unroll
        for (int nt = 0; nt < 8; ++nt) t4[nt] = sc[mt][nt];
      }
      // max3 tree: 8 vecs -> u,v,w -> vm -> pm
      f32x4 u, v, w, vm;
#pragma unroll
      for (int r = 0; r < 4; ++r) {
        u[r] = max3f(t4[0][r], t4[1][r], t4[2][r]);
        v[r] = max3f(t4[3][r], t4[4][r], t4[5][r]);
        w[r] = max3f(t4[6][r], t4[7][r], u[r]);
        vm[r] = fmaxf(v[r], w[r]);
      }
      float pm = fmaxf(max3f(vm[0], vm[1], vm[2]), vm[3]);
      pm = fmaxf(pm, __shfl_xor(pm, 16));
      pm = fmaxf(pm, __shfl_xor(pm, 32));
      // two-sided deferred rescale: fast path while pm in [mst-40, mst+16]
      if (!__all(pm <= mst[mt] + 16.0f && pm >= mst[mt] - 40.0f)) {
        float mnew = fmaxf(mst[mt], pm);
        bool fresh = (accl[mt][0] == 0.0f);
        if (fresh) mnew = pm;             // nothing accumulated: free move
        float alpha = fresh ? 0.0f : exp2f(mst[mt] - mnew);
        mst[mt] = mnew;
#pragma unroll
        for (int dt = 0; dt < 4; ++dt)
#pragma unroll
          for (int r = 0; r < 4; ++r) acc[mt][dt][r] *= alpha;
#pragma unroll
        for (int r = 0; r < 4; ++r) accl[mt][r] *= alpha;
      }
      if (__any(mst[mt] != 0.0f)) {       // rare general path: fused subtract
        const float mcur = mst[mt];
#pragma unroll
        for (int nt = 0; nt < 8; ++nt)
#pragma unroll
          for (int r = 0; r < 4; ++r) t4[nt][r] = exp2f(t4[nt][r] - mcur);
      } else {                            // common fast path: no subtract
#pragma unroll
        for (int nt = 0; nt < 8; ++nt)
#pragma unroll
          for (int r = 0; r < 4; ++r) t4[nt][r] = exp2f(t4[nt][r]);
      }
#pragma unroll
      for (int nt = 0; nt < 8; ++nt) {
        Dw[mt][nt * 2 + 0] = cvt_pk_bf16(t4[nt][0], t4[nt][1]);
        Dw[mt][nt * 2 + 1] = cvt_pk_bf16(t4[nt][2], t4[nt][3]);
      }
    }

    // ---- O^T += V^T . P^T ; l += 1^T . P^T (B-frags are Dw in registers) ----
    const short8* bu0 = (const short8*)Dw[0];
    const short8* bu1 = (const short8*)Dw[1];
    __builtin_amdgcn_s_setprio(1);
#pragma unroll
    for (int dt = 0; dt < 4; ++dt)
#pragma unroll
      for (int kf = 0; kf < 4; ++kf) {
        short8 vf = *(const short8*)(Vt + (dt * 16 + c) * 136 + kf * 32 + g * 8);
        acc[0][dt] = __builtin_amdgcn_mfma_f32_16x16x32_bf16(vf, bu0[kf], acc[0][dt], 0, 0, 0);
        acc[1][dt] = __builtin_amdgcn_mfma_f32_16x16x32_bf16(vf, bu1[kf], acc[1][dt], 0, 0, 0);
      }
#pragma unroll
    for (int kf = 0; kf < 4; ++kf) {
      accl[0] = __builtin_amdgcn_mfma_f32_16x16x32_bf16(vone, bu0[kf], accl[0], 0, 0, 0);
      accl[1] = __builtin_amdgcn_mfma_f32_16x16x32_bf16(vone, bu1[kf], accl[1], 0, 0, 0);
    }
    __builtin_amdgcn_s_setprio(0);

    // write next tile's V after all waves finished reading Vt(kt);
    // V regs are guaranteed landed (vmcnt drain at this barrier).
    if (kt < 15) {
      __syncthreads();
      writeV();
    }
  }

  // ---- epilogue: O^T col=q (per lane), rows d = dt*16 + g*4 + r ----
#pragma unroll
  for (int mt = 0; mt < 2; ++mt) {
    float rl = 1.0f / accl[mt][0];
    size_t qrow = rowbase + qt * 256 + wv * 32 + mt * 16 + c;
#pragma unroll
    for (int dt = 0; dt < 4; ++dt) {
      int d0 = h * 64 + dt * 16 + g * 4;
      float4 o;
      o.x = acc[mt][dt][0] * rl; o.y = acc[mt][dt][1] * rl;
      o.z = acc[mt][dt][2] * rl; o.w = acc[mt][dt][3] * rl;
      *(float4*)(values_f + qrow * 1024 + d0) = o;
      ushort4 ob;
      ob.x = f2b(o.x); ob.y = f2b(o.y); ob.z = f2b(o.z); ob.w = f2b(o.w);
      *(ushort4*)(values_b + qrow * 1024 + d0) = ob;
    }
  }
}

extern "C" void kernel_launch(void* const* d_in, const int* in_sizes, int n_in,
                              void* d_out, int out_size, void* d_ws, size_t ws_size,
                              hipStream_t stream) {
  const float* x    = (const float*)d_in[0];
  const float* mask = (const float*)d_in[1];
  const float* Wqkv = (const float*)d_in[2];
  const float* bqkv = (const float*)d_in[3];
  const float* Wo   = (const float*)d_in[4];
  const float* bo   = (const float*)d_in[5];
  float* out      = (float*)d_out;
  float* values_f = out + 8388608;

  char* ws = (char*)d_ws;
  ushort* xb    = (ushort*)(ws + 0);          // 16 MB  [8192,1024] bf16
  ushort* wqkvt = (ushort*)(ws + 16777216);   // 6 MB   [3072,1024] bf16 (W_qkv^T)
  ushort* wot   = (ushort*)(ws + 23068672);   // 2 MB   [1024,1024] bf16 (W_o^T)
  ushort* qkv   = (ushort*)(ws + 25165824);   // 48 MB  [8192,3072] bf16
  ushort* valb  = (ushort*)(ws + 75497472);   // 16 MB  [8192,1024] bf16
  unsigned char* mflg = (unsigned char*)(ws + 92274688);  // 256 B mask flags

  prep<<<dim3(8448), dim3(256), 0, stream>>>(x, xb, mask, mflg);
  transpose_cvt2<<<dim3(64, 16), dim3(256), 0, stream>>>(Wqkv, wqkvt, Wo, wot);
  gemm_bt_bias<0, 1><<<dim3(24, 64), dim3(256), 0, stream>>>(
      xb, wqkvt, bqkv, (void*)qkv, 8192, 3072, 1024);
  flash_attn<<<dim3(512), dim3(512), 0, stream>>>(qkv, mask, mflg, values_f, valb);
  gemm_bt_bias<1, 0><<<dim3(8, 64), dim3(256), 0, stream>>>(
      valb, wot, bo, (void*)out, 8192, 1024, 1024);
}

// Round 9
// 373.681 us; speedup vs baseline: 1.4290x; 1.4290x over previous
//
#include <hip/hip_runtime.h>
#include <hip/hip_bf16.h>

// MHA forward: x[4,2048,1024] -> qkv GEMM -> flash attention (transposed
// S^T/O^T formulation, P stays in registers) -> out proj. bf16 MFMA 16x16x32.
//
// R9 = R8 with the launch_bounds fix (R8 post-mortem: second arg follows
// CUDA semantics = min BLOCKS/CU; (512,4) forced 32 waves/CU -> 64-VGPR cap
// -> 1.4GB spill traffic, yet occupancy doubled to 43% proving the 8-wave
// concurrency theory). (512,2) -> 2 blocks/CU -> 128-VGPR cap >= natural
// ~116-124 -> no spills, 16 waves/CU.

typedef __attribute__((ext_vector_type(8))) short short8;
typedef __attribute__((ext_vector_type(4))) float f32x4;

#define SCL2E 0.1803368801111204f  /* 0.125 * log2(e) */
#define L2E   1.44269504088896340736f

#define GLD16(g, l)                                                            \
  __builtin_amdgcn_global_load_lds(                                            \
      (const __attribute__((address_space(1))) unsigned int*)(g),              \
      (__attribute__((address_space(3))) unsigned int*)(l), 16, 0, 0)

__device__ __forceinline__ unsigned short f2b(float f) {
  union { float f; unsigned int u; } v; v.f = f;
  unsigned int u = v.u;
  return (unsigned short)((u + 0x7fffu + ((u >> 16) & 1u)) >> 16);
}
__device__ __forceinline__ unsigned int fbits(float f) {
  union { float f; unsigned int u; } v; v.f = f; return v.u;
}
__device__ __forceinline__ unsigned int cvt_pk_bf16(float lo, float hi) {
  unsigned int r;
  asm("v_cvt_pk_bf16_f32 %0, %1, %2" : "=v"(r) : "v"(lo), "v"(hi));
  return r;
}
__device__ __forceinline__ float max3f(float a, float b, float c) {
  return fmaxf(fmaxf(a, b), c);   // fuses to v_max3_f32
}

// ------- prep: fp32->bf16 convert (blocks 0..8191) + mask tile byte-flags
// (blocks 8192..8447; flag (qt,kt) nonzero -> mflagsB[qt*16+kt]=1). Each
// flag byte written by exactly one block with a plain store (no reset/race).
__global__ void prep(const float* __restrict__ in, ushort* __restrict__ out,
                     const float* __restrict__ mask,
                     unsigned char* __restrict__ mflagsB) {
  const int bid = blockIdx.x;
  if (bid < 8192) {
    int i = (bid * 256 + threadIdx.x) * 4;
    float4 f = *(const float4*)(in + i);
    ushort4 o;
    o.x = f2b(f.x); o.y = f2b(f.y); o.z = f2b(f.z); o.w = f2b(f.w);
    *(ushort4*)(out + i) = o;
    return;
  }
  __shared__ unsigned int s;
  const int t = bid - 8192;            // 0..255
  const int qt = t >> 4, kt = t & 15;
  const float* base = mask + (size_t)(qt * 128) * 2048 + kt * 128;
  const int row = threadIdx.x >> 1, col0 = (threadIdx.x & 1) * 64;
  unsigned int acc = 0;
#pragma unroll
  for (int i = 0; i < 16; ++i) {
    float4 f = *(const float4*)(base + (size_t)row * 2048 + col0 + i * 4);
    acc |= fbits(f.x) | fbits(f.y) | fbits(f.z) | fbits(f.w);
  }
  acc &= 0x7fffffffu;  // treat -0.0f as zero
  if (threadIdx.x == 0) s = 0u;
  __syncthreads();
  if (acc) atomicOr(&s, 1u);
  __syncthreads();
  if (threadIdx.x == 0) mflagsB[t] = s ? 1 : 0;
}

// -- both W[K][N] fp32 -> Wt[N][K] bf16 transposes in one launch (64x64) --
__global__ void transpose_cvt2(const float* __restrict__ W1, ushort* __restrict__ Wt1,
                               const float* __restrict__ W2, ushort* __restrict__ Wt2) {
  __shared__ float tile[64][65];
  const int bx = blockIdx.x;
  const float* W; ushort* Wt; int N, n0;
  if (bx < 48) { W = W1; Wt = Wt1; N = 3072; n0 = bx * 64; }
  else         { W = W2; Wt = Wt2; N = 1024; n0 = (bx - 48) * 64; }
  const int K = 1024, k0 = blockIdx.y * 64;
  int tx = threadIdx.x & 63, ty = threadIdx.x >> 6;  // ty 0..3
#pragma unroll
  for (int i = 0; i < 64; i += 4)
    tile[ty + i][tx] = W[(size_t)(k0 + ty + i) * N + n0 + tx];
  __syncthreads();
#pragma unroll
  for (int i = 0; i < 64; i += 4)
    Wt[(size_t)(n0 + ty + i) * K + k0 + tx] = f2b(tile[tx][ty + i]);
}

// ---------------- GEMM: C[M,N] = A[M,K] @ Bt[N,K]^T + bias ----------------
// QSCALE=1: multiply q-columns (col%192 < 64) by SCL2E after bias (f32,
// before bf16 rounding) so flash_attn's score prep needs no scaling.
template <int OUTF32, int QSCALE>
__global__ __launch_bounds__(256, 2) void gemm_bt_bias(
    const ushort* __restrict__ A, const ushort* __restrict__ Bt,
    const float* __restrict__ bias, void* __restrict__ Cout,
    int M, int N, int K) {
  __shared__ ushort As[128 * 64];
  __shared__ ushort Bs[128 * 64];
  const int lane = threadIdx.x & 63;
  const int wv = threadIdx.x >> 6;
  const int bm = blockIdx.y, bn = blockIdx.x;
  const int wm = wv >> 1, wn = wv & 1;
  f32x4 acc[4][4] = {};
  const size_t arow0 = (size_t)bm * 128;
  const size_t brow0 = (size_t)bn * 128;

  for (int k0 = 0; k0 < K; k0 += 64) {
    __syncthreads();
#pragma unroll
    for (int i = 0; i < 4; ++i) {
      int r = wv * 32 + i * 8 + (lane >> 3);
      const ushort* ga = A + (arow0 + r) * K + k0 + (lane & 7) * 8;
      GLD16(ga, As + (wv * 32 + i * 8) * 64);
      const ushort* gb = Bt + (brow0 + r) * K + k0 + (lane & 7) * 8;
      GLD16(gb, Bs + (wv * 32 + i * 8) * 64);
    }
    __syncthreads();
    short8 af[2][4], bf[2][4];
#pragma unroll
    for (int kf = 0; kf < 2; ++kf)
#pragma unroll
      for (int t = 0; t < 4; ++t) {
        af[kf][t] = *(const short8*)(As + (wm * 64 + t * 16 + (lane & 15)) * 64 +
                                     kf * 32 + (lane >> 4) * 8);
        bf[kf][t] = *(const short8*)(Bs + (wn * 64 + t * 16 + (lane & 15)) * 64 +
                                     kf * 32 + (lane >> 4) * 8);
      }
#pragma unroll
    for (int kf = 0; kf < 2; ++kf)
#pragma unroll
      for (int mt = 0; mt < 4; ++mt)
#pragma unroll
        for (int nt = 0; nt < 4; ++nt)
          acc[mt][nt] = __builtin_amdgcn_mfma_f32_16x16x32_bf16(
              af[kf][mt], bf[kf][nt], acc[mt][nt], 0, 0, 0);
  }
#pragma unroll
  for (int nt = 0; nt < 4; ++nt) {
    int col = bn * 128 + wn * 64 + nt * 16 + (lane & 15);
    float bv = bias[col];
    float scl = (QSCALE && (col % 192) < 64) ? SCL2E : 1.0f;
#pragma unroll
    for (int mt = 0; mt < 4; ++mt) {
      int row0 = bm * 128 + wm * 64 + mt * 16 + (lane >> 4) * 4;
#pragma unroll
      for (int r = 0; r < 4; ++r) {
        float v = acc[mt][nt][r] + bv;
        if (QSCALE) v *= scl;
        if (OUTF32)
          ((float*)Cout)[(size_t)(row0 + r) * N + col] = v;
        else
          ((ushort*)Cout)[(size_t)(row0 + r) * N + col] = f2b(v);
      }
    }
  }
}

// ---------------- flash attention (transposed formulation) ----------------
// qkv bf16 [8192, 3072]; head h: q cols [192h,192h+64) (PRE-SCALED by SCL2E),
// k +64, v +128. Block = (b,h, qtile of 256 rows): 8 waves, each wave owns
// 32 q (2 mt). bh-fast block order. S^T = K.Q^T -> softmax in-lane;
// O^T = V^T.P^T; l via ones-MFMA. exp2-direct fast path. Ks double-buffered
// (GLD16), Vt single-buffered (reg-staged). 2 blocks/CU -> 16 waves/CU.
__global__ __launch_bounds__(512, 2) void flash_attn(
    const ushort* __restrict__ qkv, const float* __restrict__ mask,
    const unsigned char* __restrict__ mflagsB,
    float* __restrict__ values_f, ushort* __restrict__ values_b) {
  __shared__ ushort Ks[2][128 * 64];   // swizzled rows, double-buffered
  __shared__ ushort Vt[64 * 136];      // V^T, permuted key-columns, stride 136

  const int lane = threadIdx.x & 63;
  const int wv = threadIdx.x >> 6;  // 0..7
  const int c = lane & 15;          // q within mt-tile
  const int g = lane >> 4;          // key quarter-group
  const int bh = blockIdx.x & 63;   // bh FAST: concurrent blocks share mask qt
  const int qt = blockIdx.x >> 6;   // 0..7 (tiles of 256 q)
  const int b = bh >> 4, h = bh & 15;
  const size_t rowbase = (size_t)b * 2048;
  const int qcol = h * 192;
  const int swz = (c & 3) << 1;     // read-side chunk xor for Ks

  unsigned int flbits = 0;
  {
    // wave wv covers q rows [qt*256 + wv*32, +32) -> mask tile qt*2 + (wv>>2)
    const unsigned char* mb = mflagsB + (qt * 2 + (wv >> 2)) * 16;
#pragma unroll
    for (int i = 0; i < 16; ++i) flbits |= (mb[i] ? 1u : 0u) << i;
  }

  // all-ones bf16 A-fragment (1.0 = 0x3F80) for the l-sum MFMA
  const short8 vone = {0x3F80, 0x3F80, 0x3F80, 0x3F80,
                       0x3F80, 0x3F80, 0x3F80, 0x3F80};

  // Q b-frags straight from global (pre-scaled by SCL2E in GEMM epilogue)
  short8 qf[2][2];
#pragma unroll
  for (int mt = 0; mt < 2; ++mt)
#pragma unroll
    for (int kf = 0; kf < 2; ++kf)
      qf[mt][kf] = *(const short8*)(qkv +
          (rowbase + qt * 256 + wv * 32 + mt * 16 + c) * 3072 + qcol +
          kf * 32 + g * 8);

  f32x4 acc[2][4] = {};
  f32x4 accl[2] = {};               // l-sum accumulator (all 4 rows identical)
  float mst[2] = {0.f, 0.f};        // exp2-direct: base offset, 0 = no offset

  // V staging mapping: thread -> key pair (K0,K0+1), d-eighth dq (8 d-elems)
  const int K0 = lane * 2;
  const int dq = wv;                 // 0..7
  const int pc0 = ((K0 >> 5) << 5) + (((K0 >> 2) & 3) << 3) +
                  (((K0 >> 4) & 1) << 2) + (K0 & 3);   // permuted column of K0
  const int vdw = pc0 >> 1;                            // dword column
  const int gcol = (((lane & 7) ^ (((lane >> 3) & 3) << 1)) << 3);

  short8 va0, vb0;                  // in-flight V regs for next tile

  auto loadV = [&](int t) {
    const ushort* vg = qkv + (rowbase + t * 128 + K0) * 3072 + qcol + 128 + dq * 8;
    va0 = *(const short8*)(vg);
    vb0 = *(const short8*)(vg + 3072);
  };
  auto writeV = [&]() {
    unsigned int* Vdw = (unsigned int*)Vt;
    const unsigned int* aw0 = (const unsigned int*)&va0;
    const unsigned int* bw0 = (const unsigned int*)&vb0;
#pragma unroll
    for (int k = 0; k < 4; ++k) {
      Vdw[(dq * 8 + 2 * k + 0) * 68 + vdw] =
          __builtin_amdgcn_perm(bw0[k], aw0[k], 0x05040100u);
      Vdw[(dq * 8 + 2 * k + 1) * 68 + vdw] =
          __builtin_amdgcn_perm(bw0[k], aw0[k], 0x07060302u);
    }
  };
  auto stageK = [&](int t, ushort* KsD) {
#pragma unroll
    for (int i = 0; i < 2; ++i) {
      int rloc = wv * 16 + i * 8;
      const ushort* gk = qkv + (rowbase + t * 128 + rloc + (lane >> 3)) * 3072 +
                         qcol + 64 + gcol;
      GLD16(gk, KsD + rloc * 64);
    }
  };

  const float* mrow = mask + (size_t)(qt * 256 + wv * 32 + c) * 2048 + g * 4;

  // ---- prologue: stage tile 0 ----
  loadV(0);
  stageK(0, Ks[0]);
  writeV();

  for (int kt = 0; kt < 16; ++kt) {
    __syncthreads();               // Ks[cur](kt) + Vt(kt) ready
    const int cur = kt & 1;
    const ushort* KsC = Ks[cur];
    // issue next tile's loads; latency hides under QK/softmax/PV below
    if (kt < 15) {
      loadV(kt + 1);
      stageK(kt + 1, Ks[cur ^ 1]);
    }

    const bool hasmask = (flbits >> kt) & 1u;
    const float* mkt = mrow + kt * 128;
    // mask for mt=0 issued early (overlaps QK MFMAs); skipped for zero tiles
    float4 msk0[8];
    if (hasmask) {
#pragma unroll
      for (int nt = 0; nt < 8; ++nt) msk0[nt] = *(const float4*)(mkt + nt * 16);
    }

    // ---- S^T = K . Q^T ----
    f32x4 sc[2][8];
    __builtin_amdgcn_s_setprio(1);
#pragma unroll
    for (int nt = 0; nt < 8; ++nt) {
      short8 k0 = *(const short8*)(KsC + (nt * 16 + c) * 64 + ((g ^ swz) << 3));
      short8 k1 = *(const short8*)(KsC + (nt * 16 + c) * 64 + (((4 + g) ^ swz) << 3));
      f32x4 z = {0.f, 0.f, 0.f, 0.f};
      sc[0][nt] = __builtin_amdgcn_mfma_f32_16x16x32_bf16(k0, qf[0][0], z, 0, 0, 0);
      sc[0][nt] = __builtin_amdgcn_mfma_f32_16x16x32_bf16(k1, qf[0][1], sc[0][nt], 0, 0, 0);
      sc[1][nt] = __builtin_amdgcn_mfma_f32_16x16x32_bf16(k0, qf[1][0], z, 0, 0, 0);
      sc[1][nt] = __builtin_amdgcn_mfma_f32_16x16x32_bf16(k1, qf[1][1], sc[1][nt], 0, 0, 0);
    }
    __builtin_amdgcn_s_setprio(0);

    // ---- online softmax (exp2-direct; in-lane keys) ----
    __attribute__((aligned(16))) unsigned int Dw[2][16];
#pragma unroll
    for (int mt = 0; mt < 2; ++mt) {
      f32x4 t4[8];
      if (hasmask) {
#pragma unroll
        for (int nt = 0; nt < 8; ++nt) {
          float4 mk = (mt == 0) ? msk0[nt]
                                : *(const float4*)(mkt + 16 * 2048 + nt * 16);
#pragma unroll
          for (int r = 0; r < 4; ++r)
            t4[nt][r] = fmaf(((const float*)&mk)[r], L2E, sc[mt][nt][r]);
        }
      } else {
#pragma unroll
        for (int nt = 0; nt < 8; ++nt) t4[nt] = sc[mt][nt];
      }
      // max3 tree: 8 vecs -> u,v,w -> vm -> pm
      f32x4 u, v, w, vm;
#pragma unroll
      for (int r = 0; r < 4; ++r) {
        u[r] = max3f(t4[0][r], t4[1][r], t4[2][r]);
        v[r] = max3f(t4[3][r], t4[4][r], t4[5][r]);
        w[r] = max3f(t4[6][r], t4[7][r], u[r]);
        vm[r] = fmaxf(v[r], w[r]);
      }
      float pm = fmaxf(max3f(vm[0], vm[1], vm[2]), vm[3]);
      pm = fmaxf(pm, __shfl_xor(pm, 16));
      pm = fmaxf(pm, __shfl_xor(pm, 32));
      // two-sided deferred rescale: fast path while pm in [mst-40, mst+16]
      if (!__all(pm <= mst[mt] + 16.0f && pm >= mst[mt] - 40.0f)) {
        float mnew = fmaxf(mst[mt], pm);
        bool fresh = (accl[mt][0] == 0.0f);
        if (fresh) mnew = pm;             // nothing accumulated: free move
        float alpha = fresh ? 0.0f : exp2f(mst[mt] - mnew);
        mst[mt] = mnew;
#pragma unroll
        for (int dt = 0; dt < 4; ++dt)
#pragma unroll
          for (int r = 0; r < 4; ++r) acc[mt][dt][r] *= alpha;
#pragma unroll
        for (int r = 0; r < 4; ++r) accl[mt][r] *= alpha;
      }
      if (__any(mst[mt] != 0.0f)) {       // rare general path: fused subtract
        const float mcur = mst[mt];
#pragma unroll
        for (int nt = 0; nt < 8; ++nt)
#pragma unroll
          for (int r = 0; r < 4; ++r) t4[nt][r] = exp2f(t4[nt][r] - mcur);
      } else {                            // common fast path: no subtract
#pragma unroll
        for (int nt = 0; nt < 8; ++nt)
#pragma unroll
          for (int r = 0; r < 4; ++r) t4[nt][r] = exp2f(t4[nt][r]);
      }
#pragma unroll
      for (int nt = 0; nt < 8; ++nt) {
        Dw[mt][nt * 2 + 0] = cvt_pk_bf16(t4[nt][0], t4[nt][1]);
        Dw[mt][nt * 2 + 1] = cvt_pk_bf16(t4[nt][2], t4[nt][3]);
      }
    }

    // ---- O^T += V^T . P^T ; l += 1^T . P^T (B-frags are Dw in registers) ----
    const short8* bu0 = (const short8*)Dw[0];
    const short8* bu1 = (const short8*)Dw[1];
    __builtin_amdgcn_s_setprio(1);
#pragma unroll
    for (int dt = 0; dt < 4; ++dt)
#pragma unroll
      for (int kf = 0; kf < 4; ++kf) {
        short8 vf = *(const short8*)(Vt + (dt * 16 + c) * 136 + kf * 32 + g * 8);
        acc[0][dt] = __builtin_amdgcn_mfma_f32_16x16x32_bf16(vf, bu0[kf], acc[0][dt], 0, 0, 0);
        acc[1][dt] = __builtin_amdgcn_mfma_f32_16x16x32_bf16(vf, bu1[kf], acc[1][dt], 0, 0, 0);
      }
#pragma unroll
    for (int kf = 0; kf < 4; ++kf) {
      accl[0] = __builtin_amdgcn_mfma_f32_16x16x32_bf16(vone, bu0[kf], accl[0], 0, 0, 0);
      accl[1] = __builtin_amdgcn_mfma_f32_16x16x32_bf16(vone, bu1[kf], accl[1], 0, 0, 0);
    }
    __builtin_amdgcn_s_setprio(0);

    // write next tile's V after all waves finished reading Vt(kt);
    // V regs are guaranteed landed (vmcnt drain at this barrier).
    if (kt < 15) {
      __syncthreads();
      writeV();
    }
  }

  // ---- epilogue: O^T col=q (per lane), rows d = dt*16 + g*4 + r ----
#pragma unroll
  for (int mt = 0; mt < 2; ++mt) {
    float rl = 1.0f / accl[mt][0];
    size_t qrow = rowbase + qt * 256 + wv * 32 + mt * 16 + c;
#pragma unroll
    for (int dt = 0; dt < 4; ++dt) {
      int d0 = h * 64 + dt * 16 + g * 4;
      float4 o;
      o.x = acc[mt][dt][0] * rl; o.y = acc[mt][dt][1] * rl;
      o.z = acc[mt][dt][2] * rl; o.w = acc[mt][dt][3] * rl;
      *(float4*)(values_f + qrow * 1024 + d0) = o;
      ushort4 ob;
      ob.x = f2b(o.x); ob.y = f2b(o.y); ob.z = f2b(o.z); ob.w = f2b(o.w);
      *(ushort4*)(values_b + qrow * 1024 + d0) = ob;
    }
  }
}

extern "C" void kernel_launch(void* const* d_in, const int* in_sizes, int n_in,
                              void* d_out, int out_size, void* d_ws, size_t ws_size,
                              hipStream_t stream) {
  const float* x    = (const float*)d_in[0];
  const float* mask = (const float*)d_in[1];
  const float* Wqkv = (const float*)d_in[2];
  const float* bqkv = (const float*)d_in[3];
  const float* Wo   = (const float*)d_in[4];
  const float* bo   = (const float*)d_in[5];
  float* out      = (float*)d_out;
  float* values_f = out + 8388608;

  char* ws = (char*)d_ws;
  ushort* xb    = (ushort*)(ws + 0);          // 16 MB  [8192,1024] bf16
  ushort* wqkvt = (ushort*)(ws + 16777216);   // 6 MB   [3072,1024] bf16 (W_qkv^T)
  ushort* wot   = (ushort*)(ws + 23068672);   // 2 MB   [1024,1024] bf16 (W_o^T)
  ushort* qkv   = (ushort*)(ws + 25165824);   // 48 MB  [8192,3072] bf16
  ushort* valb  = (ushort*)(ws + 75497472);   // 16 MB  [8192,1024] bf16
  unsigned char* mflg = (unsigned char*)(ws + 92274688);  // 256 B mask flags

  prep<<<dim3(8448), dim3(256), 0, stream>>>(x, xb, mask, mflg);
  transpose_cvt2<<<dim3(64, 16), dim3(256), 0, stream>>>(Wqkv, wqkvt, Wo, wot);
  gemm_bt_bias<0, 1><<<dim3(24, 64), dim3(256), 0, stream>>>(
      xb, wqkvt, bqkv, (void*)qkv, 8192, 3072, 1024);
  flash_attn<<<dim3(512), dim3(512), 0, stream>>>(qkv, mask, mflg, values_f, valb);
  gemm_bt_bias<1, 0><<<dim3(8, 64), dim3(256), 0, stream>>>(
      valb, wot, bo, (void*)out, 8192, 1024, 1024);
}

// Round 11
// 352.626 us; speedup vs baseline: 1.5143x; 1.0597x over previous
//
#include <hip/hip_runtime.h>
#include <hip/hip_bf16.h>

// MHA forward: x[4,2048,1024] -> qkv GEMM -> flash attention (transposed
// S^T/O^T formulation, P stays in registers) -> out proj. bf16 MFMA 16x16x32.
//
// R11 = R10 resubmit (R10 bench was an infra failure; kernel audited: no
// divergent barriers, all bounds checked, graph-capture-safe).
// R10 changes vs R6 (356.0us best-verified):
//  - fused QK+softmax pipeline (fast path): FIN(nt-1) VALU/TRANS work is
//    interleaved with MFMAs(nt) -> MFMA and VALU pipes overlap in-wave.
//    Guard checked after; rare trip recomputes from live sc; 'clean' flag
//    falls back to exact general online-softmax for arbitrary masks/data.
//  - prep + mask-flags + both weight transposes fused into ONE kernel:
//    4 launches total.
//  - keep: exp2-direct, l-sum via ones-MFMA, mask zero-tile skip, Q
//    pre-scale in GEMM, cvt_pk pack, v_perm writeV, setprio on PV.

typedef __attribute__((ext_vector_type(8))) short short8;
typedef __attribute__((ext_vector_type(4))) float f32x4;

#define SCL2E 0.1803368801111204f  /* 0.125 * log2(e) */
#define L2E   1.44269504088896340736f

#define GLD16(g, l)                                                            \
  __builtin_amdgcn_global_load_lds(                                            \
      (const __attribute__((address_space(1))) unsigned int*)(g),              \
      (__attribute__((address_space(3))) unsigned int*)(l), 16, 0, 0)

__device__ __forceinline__ unsigned short f2b(float f) {
  union { float f; unsigned int u; } v; v.f = f;
  unsigned int u = v.u;
  return (unsigned short)((u + 0x7fffu + ((u >> 16) & 1u)) >> 16);
}
__device__ __forceinline__ unsigned int fbits(float f) {
  union { float f; unsigned int u; } v; v.f = f; return v.u;
}
__device__ __forceinline__ unsigned int cvt_pk_bf16(float lo, float hi) {
  unsigned int r;
  asm("v_cvt_pk_bf16_f32 %0, %1, %2" : "=v"(r) : "v"(lo), "v"(hi));
  return r;
}
__device__ __forceinline__ float max3f(float a, float b, float c) {
  return fmaxf(fmaxf(a, b), c);   // fuses to v_max3_f32
}

// ---- prep_all: one launch. blocks 0..8191: x fp32->bf16. 8192..8447: mask
// tile byte-flags. 8448..9471: both weight transposes (fp32 -> bf16^T). ----
__global__ void prep_all(const float* __restrict__ in, ushort* __restrict__ out,
                         const float* __restrict__ mask,
                         unsigned char* __restrict__ mflagsB,
                         const float* __restrict__ W1, ushort* __restrict__ Wt1,
                         const float* __restrict__ W2, ushort* __restrict__ Wt2) {
  const int bid = blockIdx.x;
  if (bid < 8192) {
    int i = (bid * 256 + threadIdx.x) * 4;
    float4 f = *(const float4*)(in + i);
    ushort4 o;
    o.x = f2b(f.x); o.y = f2b(f.y); o.z = f2b(f.z); o.w = f2b(f.w);
    *(ushort4*)(out + i) = o;
    return;
  }
  if (bid < 8448) {
    __shared__ unsigned int s;
    const int t = bid - 8192;            // 0..255
    const int qt = t >> 4, kt = t & 15;
    const float* base = mask + (size_t)(qt * 128) * 2048 + kt * 128;
    const int row = threadIdx.x >> 1, col0 = (threadIdx.x & 1) * 64;
    unsigned int acc = 0;
#pragma unroll
    for (int i = 0; i < 16; ++i) {
      float4 f = *(const float4*)(base + (size_t)row * 2048 + col0 + i * 4);
      acc |= fbits(f.x) | fbits(f.y) | fbits(f.z) | fbits(f.w);
    }
    acc &= 0x7fffffffu;  // treat -0.0f as zero
    if (threadIdx.x == 0) s = 0u;
    __syncthreads();
    if (acc) atomicOr(&s, 1u);
    __syncthreads();
    if (threadIdx.x == 0) mflagsB[t] = s ? 1 : 0;
    return;
  }
  // transpose: t2 in [0,1024): bx = t2&63 selects matrix+col, by = t2>>6 row
  __shared__ float tile[64][65];
  const int t2 = bid - 8448;
  const int bx = t2 & 63, by = t2 >> 6;
  const float* W; ushort* Wt; int N, n0;
  if (bx < 48) { W = W1; Wt = Wt1; N = 3072; n0 = bx * 64; }
  else         { W = W2; Wt = Wt2; N = 1024; n0 = (bx - 48) * 64; }
  const int K = 1024, k0 = by * 64;
  int tx = threadIdx.x & 63, ty = threadIdx.x >> 6;  // ty 0..3
#pragma unroll
  for (int i = 0; i < 64; i += 4)
    tile[ty + i][tx] = W[(size_t)(k0 + ty + i) * N + n0 + tx];
  __syncthreads();
#pragma unroll
  for (int i = 0; i < 64; i += 4)
    Wt[(size_t)(n0 + ty + i) * K + k0 + tx] = f2b(tile[tx][ty + i]);
}

// ---------------- GEMM: C[M,N] = A[M,K] @ Bt[N,K]^T + bias ----------------
// QSCALE=1: multiply q-columns (col%192 < 64) by SCL2E after bias (f32,
// before bf16 rounding) so flash_attn's score prep needs no scaling.
template <int OUTF32, int QSCALE>
__global__ __launch_bounds__(256, 2) void gemm_bt_bias(
    const ushort* __restrict__ A, const ushort* __restrict__ Bt,
    const float* __restrict__ bias, void* __restrict__ Cout,
    int M, int N, int K) {
  __shared__ ushort As[128 * 64];
  __shared__ ushort Bs[128 * 64];
  const int lane = threadIdx.x & 63;
  const int wv = threadIdx.x >> 6;
  const int bm = blockIdx.y, bn = blockIdx.x;
  const int wm = wv >> 1, wn = wv & 1;
  f32x4 acc[4][4] = {};
  const size_t arow0 = (size_t)bm * 128;
  const size_t brow0 = (size_t)bn * 128;

  for (int k0 = 0; k0 < K; k0 += 64) {
    __syncthreads();
#pragma unroll
    for (int i = 0; i < 4; ++i) {
      int r = wv * 32 + i * 8 + (lane >> 3);
      const ushort* ga = A + (arow0 + r) * K + k0 + (lane & 7) * 8;
      GLD16(ga, As + (wv * 32 + i * 8) * 64);
      const ushort* gb = Bt + (brow0 + r) * K + k0 + (lane & 7) * 8;
      GLD16(gb, Bs + (wv * 32 + i * 8) * 64);
    }
    __syncthreads();
    short8 af[2][4], bf[2][4];
#pragma unroll
    for (int kf = 0; kf < 2; ++kf)
#pragma unroll
      for (int t = 0; t < 4; ++t) {
        af[kf][t] = *(const short8*)(As + (wm * 64 + t * 16 + (lane & 15)) * 64 +
                                     kf * 32 + (lane >> 4) * 8);
        bf[kf][t] = *(const short8*)(Bs + (wn * 64 + t * 16 + (lane & 15)) * 64 +
                                     kf * 32 + (lane >> 4) * 8);
      }
#pragma unroll
    for (int kf = 0; kf < 2; ++kf)
#pragma unroll
      for (int mt = 0; mt < 4; ++mt)
#pragma unroll
        for (int nt = 0; nt < 4; ++nt)
          acc[mt][nt] = __builtin_amdgcn_mfma_f32_16x16x32_bf16(
              af[kf][mt], bf[kf][nt], acc[mt][nt], 0, 0, 0);
  }
#pragma unroll
  for (int nt = 0; nt < 4; ++nt) {
    int col = bn * 128 + wn * 64 + nt * 16 + (lane & 15);
    float bv = bias[col];
    float scl = (QSCALE && (col % 192) < 64) ? SCL2E : 1.0f;
#pragma unroll
    for (int mt = 0; mt < 4; ++mt) {
      int row0 = bm * 128 + wm * 64 + mt * 16 + (lane >> 4) * 4;
#pragma unroll
      for (int r = 0; r < 4; ++r) {
        float v = acc[mt][nt][r] + bv;
        if (QSCALE) v *= scl;
        if (OUTF32)
          ((float*)Cout)[(size_t)(row0 + r) * N + col] = v;
        else
          ((ushort*)Cout)[(size_t)(row0 + r) * N + col] = f2b(v);
      }
    }
  }
}

// ---------------- flash attention (transposed formulation) ----------------
// qkv bf16 [8192, 3072]; head h: q cols [192h,192h+64) (PRE-SCALED by SCL2E),
// k +64, v +128. Block = (b,h,qtile of 128 rows), bh-fast block order.
// S^T = K.Q^T; fused QK+softmax pipeline (exp2-direct fast path overlaps
// MFMA and VALU pipes); O^T = V^T.P^T; l via ones-MFMA. Ks double-buffered
// (GLD16), Vt single-buffered (reg-staged). 2 barriers per kt.
__global__ __launch_bounds__(256, 2) void flash_attn(
    const ushort* __restrict__ qkv, const float* __restrict__ mask,
    const unsigned char* __restrict__ mflagsB,
    float* __restrict__ values_f, ushort* __restrict__ values_b) {
  __shared__ ushort Ks[2][128 * 64];   // swizzled rows, double-buffered
  __shared__ ushort Vt[64 * 136];      // V^T, permuted key-columns, stride 136

  const int lane = threadIdx.x & 63;
  const int wv = threadIdx.x >> 6;
  const int c = lane & 15;          // q within mt-tile
  const int g = lane >> 4;          // key quarter-group
  const int bh = blockIdx.x & 63;   // bh FAST: concurrent blocks share mask qt
  const int qt = blockIdx.x >> 6;
  const int b = bh >> 4, h = bh & 15;
  const size_t rowbase = (size_t)b * 2048;
  const int qcol = h * 192;
  const int swz = (c & 3) << 1;     // read-side chunk xor for Ks

  unsigned int flbits = 0;
  {
    const unsigned char* mb = mflagsB + qt * 16;
#pragma unroll
    for (int i = 0; i < 16; ++i) flbits |= (mb[i] ? 1u : 0u) << i;
  }

  // all-ones bf16 A-fragment (1.0 = 0x3F80) for the l-sum MFMA
  const short8 vone = {0x3F80, 0x3F80, 0x3F80, 0x3F80,
                       0x3F80, 0x3F80, 0x3F80, 0x3F80};

  // Q b-frags straight from global (pre-scaled by SCL2E in GEMM epilogue)
  short8 qf[2][2];
#pragma unroll
  for (int mt = 0; mt < 2; ++mt)
#pragma unroll
    for (int kf = 0; kf < 2; ++kf)
      qf[mt][kf] = *(const short8*)(qkv +
          (rowbase + qt * 128 + wv * 32 + mt * 16 + c) * 3072 + qcol +
          kf * 32 + g * 8);

  f32x4 acc[2][4] = {};
  f32x4 accl[2] = {};               // l-sum accumulator (all 4 rows identical)
  float mst[2] = {0.f, 0.f};        // exp2-direct base offset (0 = none)
  bool clean = true;                // no guard trip yet (fast path valid)

  // V staging mapping: thread -> key pair (K0,K0+1), d-quarter dq
  const int K0 = lane * 2;
  const int dq = wv;
  const int pc0 = ((K0 >> 5) << 5) + (((K0 >> 2) & 3) << 3) +
                  (((K0 >> 4) & 1) << 2) + (K0 & 3);   // permuted column of K0
  const int vdw = pc0 >> 1;                            // dword column
  const int gcol = (((lane & 7) ^ (((lane >> 3) & 3) << 1)) << 3);

  short8 va0, va1, vb0, vb1;        // in-flight V regs for next tile

  auto loadV = [&](int t) {
    const ushort* vg = qkv + (rowbase + t * 128 + K0) * 3072 + qcol + 128 + dq * 16;
    va0 = *(const short8*)(vg);
    va1 = *(const short8*)(vg + 8);
    vb0 = *(const short8*)(vg + 3072);
    vb1 = *(const short8*)(vg + 3072 + 8);
  };
  auto writeV = [&]() {
    unsigned int* Vdw = (unsigned int*)Vt;
    const unsigned int* aw0 = (const unsigned int*)&va0;
    const unsigned int* bw0 = (const unsigned int*)&vb0;
    const unsigned int* aw1 = (const unsigned int*)&va1;
    const unsigned int* bw1 = (const unsigned int*)&vb1;
#pragma unroll
    for (int k = 0; k < 4; ++k) {
      Vdw[(dq * 16 + 2 * k + 0) * 68 + vdw] =
          __builtin_amdgcn_perm(bw0[k], aw0[k], 0x05040100u);
      Vdw[(dq * 16 + 2 * k + 1) * 68 + vdw] =
          __builtin_amdgcn_perm(bw0[k], aw0[k], 0x07060302u);
    }
#pragma unroll
    for (int k = 0; k < 4; ++k) {
      Vdw[(dq * 16 + 8 + 2 * k + 0) * 68 + vdw] =
          __builtin_amdgcn_perm(bw1[k], aw1[k], 0x05040100u);
      Vdw[(dq * 16 + 8 + 2 * k + 1) * 68 + vdw] =
          __builtin_amdgcn_perm(bw1[k], aw1[k], 0x07060302u);
    }
  };
  auto stageK = [&](int t, ushort* KsD) {
#pragma unroll
    for (int i = 0; i < 4; ++i) {
      int rloc = wv * 32 + i * 8;
      const ushort* gk = qkv + (rowbase + t * 128 + rloc + (lane >> 3)) * 3072 +
                         qcol + 64 + gcol;
      GLD16(gk, KsD + rloc * 64);
    }
  };

  const float* mrow = mask + (size_t)(qt * 128 + wv * 32 + c) * 2048 + g * 4;

  // ---- prologue: stage tile 0 ----
  loadV(0);
  stageK(0, Ks[0]);
  writeV();

  for (int kt = 0; kt < 16; ++kt) {
    __syncthreads();               // Ks[cur](kt) + Vt(kt) ready
    const int cur = kt & 1;
    const ushort* KsC = Ks[cur];
    // issue next tile's loads; latency hides under QK/softmax/PV below
    if (kt < 15) {
      loadV(kt + 1);
      stageK(kt + 1, Ks[cur ^ 1]);
    }

    const bool hasmask = (flbits >> kt) & 1u;
    const float* mkt = mrow + kt * 128;
    // mask for mt=0 issued early (overlaps QK MFMAs); skipped for zero tiles
    float4 msk0[8];
    if (hasmask) {
#pragma unroll
      for (int nt = 0; nt < 8; ++nt) msk0[nt] = *(const float4*)(mkt + nt * 16);
    }

    f32x4 sc[2][8];
    __attribute__((aligned(16))) unsigned int Dw[2][16];

    if (clean) {
      // ---- fused QK + softmax pipeline (fast path: p = exp2(t), no sub) ----
      f32x4 vmx[2];
      vmx[0] = f32x4{-3e38f, -3e38f, -3e38f, -3e38f};
      vmx[1] = vmx[0];
      auto FIN = [&](int j) {
#pragma unroll
        for (int mt = 0; mt < 2; ++mt) {
          f32x4 t4;
          if (hasmask) {
            float4 mk = (mt == 0) ? msk0[j]
                                  : *(const float4*)(mkt + 16 * 2048 + j * 16);
#pragma unroll
            for (int r = 0; r < 4; ++r)
              t4[r] = fmaf(((const float*)&mk)[r], L2E, sc[mt][j][r]);
            sc[mt][j] = t4;      // keep mask-applied score for rare recompute
          } else {
            t4 = sc[mt][j];
          }
#pragma unroll
          for (int r = 0; r < 4; ++r) vmx[mt][r] = fmaxf(vmx[mt][r], t4[r]);
          float p0 = exp2f(t4[0]), p1 = exp2f(t4[1]);
          float p2 = exp2f(t4[2]), p3 = exp2f(t4[3]);
          Dw[mt][j * 2 + 0] = cvt_pk_bf16(p0, p1);
          Dw[mt][j * 2 + 1] = cvt_pk_bf16(p2, p3);
        }
      };
      __builtin_amdgcn_s_setprio(1);
#pragma unroll
      for (int nt = 0; nt < 8; ++nt) {
        short8 k0 = *(const short8*)(KsC + (nt * 16 + c) * 64 + ((g ^ swz) << 3));
        short8 k1 = *(const short8*)(KsC + (nt * 16 + c) * 64 + (((4 + g) ^ swz) << 3));
        f32x4 z = {0.f, 0.f, 0.f, 0.f};
        sc[0][nt] = __builtin_amdgcn_mfma_f32_16x16x32_bf16(k0, qf[0][0], z, 0, 0, 0);
        sc[0][nt] = __builtin_amdgcn_mfma_f32_16x16x32_bf16(k1, qf[0][1], sc[0][nt], 0, 0, 0);
        sc[1][nt] = __builtin_amdgcn_mfma_f32_16x16x32_bf16(k0, qf[1][0], z, 0, 0, 0);
        sc[1][nt] = __builtin_amdgcn_mfma_f32_16x16x32_bf16(k1, qf[1][1], sc[1][nt], 0, 0, 0);
        if (nt > 0) FIN(nt - 1);   // overlap prev-stage VALU with these MFMAs
      }
      FIN(7);
      __builtin_amdgcn_s_setprio(0);
      // guard: fast path valid while pm in [-40, +16] (mst == 0)
#pragma unroll
      for (int mt = 0; mt < 2; ++mt) {
        float pm = fmaxf(max3f(vmx[mt][0], vmx[mt][1], vmx[mt][2]), vmx[mt][3]);
        pm = fmaxf(pm, __shfl_xor(pm, 16));
        pm = fmaxf(pm, __shfl_xor(pm, 32));
        if (!__all(pm <= 16.0f && pm >= -40.0f)) {
          clean = false;
          float mnew = fmaxf(0.0f, pm);
          bool fresh = (accl[mt][0] == 0.0f);
          if (fresh) mnew = pm;
          float alpha = fresh ? 0.0f : exp2f(-mnew);
          mst[mt] = mnew;
#pragma unroll
          for (int dt = 0; dt < 4; ++dt)
#pragma unroll
            for (int r = 0; r < 4; ++r) acc[mt][dt][r] *= alpha;
#pragma unroll
          for (int r = 0; r < 4; ++r) accl[mt][r] *= alpha;
#pragma unroll
          for (int j = 0; j < 8; ++j) {   // recompute with subtraction
            float p0 = exp2f(sc[mt][j][0] - mnew), p1 = exp2f(sc[mt][j][1] - mnew);
            float p2 = exp2f(sc[mt][j][2] - mnew), p3 = exp2f(sc[mt][j][3] - mnew);
            Dw[mt][j * 2 + 0] = cvt_pk_bf16(p0, p1);
            Dw[mt][j * 2 + 1] = cvt_pk_bf16(p2, p3);
          }
        }
      }
    } else {
      // ---- general online-softmax path (after any guard trip) ----
      __builtin_amdgcn_s_setprio(1);
#pragma unroll
      for (int nt = 0; nt < 8; ++nt) {
        short8 k0 = *(const short8*)(KsC + (nt * 16 + c) * 64 + ((g ^ swz) << 3));
        short8 k1 = *(const short8*)(KsC + (nt * 16 + c) * 64 + (((4 + g) ^ swz) << 3));
        f32x4 z = {0.f, 0.f, 0.f, 0.f};
        sc[0][nt] = __builtin_amdgcn_mfma_f32_16x16x32_bf16(k0, qf[0][0], z, 0, 0, 0);
        sc[0][nt] = __builtin_amdgcn_mfma_f32_16x16x32_bf16(k1, qf[0][1], sc[0][nt], 0, 0, 0);
        sc[1][nt] = __builtin_amdgcn_mfma_f32_16x16x32_bf16(k0, qf[1][0], z, 0, 0, 0);
        sc[1][nt] = __builtin_amdgcn_mfma_f32_16x16x32_bf16(k1, qf[1][1], sc[1][nt], 0, 0, 0);
      }
      __builtin_amdgcn_s_setprio(0);
#pragma unroll
      for (int mt = 0; mt < 2; ++mt) {
        f32x4 t4[8];
        if (hasmask) {
#pragma unroll
          for (int nt = 0; nt < 8; ++nt) {
            float4 mk = (mt == 0) ? msk0[nt]
                                  : *(const float4*)(mkt + 16 * 2048 + nt * 16);
#pragma unroll
            for (int r = 0; r < 4; ++r)
              t4[nt][r] = fmaf(((const float*)&mk)[r], L2E, sc[mt][nt][r]);
          }
        } else {
#pragma unroll
          for (int nt = 0; nt < 8; ++nt) t4[nt] = sc[mt][nt];
        }
        f32x4 u, v, w, vm;
#pragma unroll
        for (int r = 0; r < 4; ++r) {
          u[r] = max3f(t4[0][r], t4[1][r], t4[2][r]);
          v[r] = max3f(t4[3][r], t4[4][r], t4[5][r]);
          w[r] = max3f(t4[6][r], t4[7][r], u[r]);
          vm[r] = fmaxf(v[r], w[r]);
        }
        float pm = fmaxf(max3f(vm[0], vm[1], vm[2]), vm[3]);
        pm = fmaxf(pm, __shfl_xor(pm, 16));
        pm = fmaxf(pm, __shfl_xor(pm, 32));
        if (!__all(pm <= mst[mt] + 16.0f && pm >= mst[mt] - 40.0f)) {
          float mnew = fmaxf(mst[mt], pm);
          bool fresh = (accl[mt][0] == 0.0f);
          if (fresh) mnew = pm;
          float alpha = fresh ? 0.0f : exp2f(mst[mt] - mnew);
          mst[mt] = mnew;
#pragma unroll
          for (int dt = 0; dt < 4; ++dt)
#pragma unroll
            for (int r = 0; r < 4; ++r) acc[mt][dt][r] *= alpha;
#pragma unroll
          for (int r = 0; r < 4; ++r) accl[mt][r] *= alpha;
        }
        const float mcur = mst[mt];
#pragma unroll
        for (int nt = 0; nt < 8; ++nt) {
          float p0 = exp2f(t4[nt][0] - mcur), p1 = exp2f(t4[nt][1] - mcur);
          float p2 = exp2f(t4[nt][2] - mcur), p3 = exp2f(t4[nt][3] - mcur);
          Dw[mt][nt * 2 + 0] = cvt_pk_bf16(p0, p1);
          Dw[mt][nt * 2 + 1] = cvt_pk_bf16(p2, p3);
        }
      }
    }

    // ---- O^T += V^T . P^T ; l += 1^T . P^T (B-frags are Dw in registers) ----
    const short8* bu0 = (const short8*)Dw[0];
    const short8* bu1 = (const short8*)Dw[1];
    __builtin_amdgcn_s_setprio(1);
#pragma unroll
    for (int dt = 0; dt < 4; ++dt)
#pragma unroll
      for (int kf = 0; kf < 4; ++kf) {
        short8 vf = *(const short8*)(Vt + (dt * 16 + c) * 136 + kf * 32 + g * 8);
        acc[0][dt] = __builtin_amdgcn_mfma_f32_16x16x32_bf16(vf, bu0[kf], acc[0][dt], 0, 0, 0);
        acc[1][dt] = __builtin_amdgcn_mfma_f32_16x16x32_bf16(vf, bu1[kf], acc[1][dt], 0, 0, 0);
      }
#pragma unroll
    for (int kf = 0; kf < 4; ++kf) {
      accl[0] = __builtin_amdgcn_mfma_f32_16x16x32_bf16(vone, bu0[kf], accl[0], 0, 0, 0);
      accl[1] = __builtin_amdgcn_mfma_f32_16x16x32_bf16(vone, bu1[kf], accl[1], 0, 0, 0);
    }
    __builtin_amdgcn_s_setprio(0);

    // write next tile's V after all waves finished reading Vt(kt);
    // V regs are guaranteed landed (vmcnt drain at this barrier).
    if (kt < 15) {
      __syncthreads();
      writeV();
    }
  }

  // ---- epilogue: O^T col=q (per lane), rows d = dt*16 + g*4 + r ----
#pragma unroll
  for (int mt = 0; mt < 2; ++mt) {
    float rl = 1.0f / accl[mt][0];
    size_t qrow = rowbase + qt * 128 + wv * 32 + mt * 16 + c;
#pragma unroll
    for (int dt = 0; dt < 4; ++dt) {
      int d0 = h * 64 + dt * 16 + g * 4;
      float4 o;
      o.x = acc[mt][dt][0] * rl; o.y = acc[mt][dt][1] * rl;
      o.z = acc[mt][dt][2] * rl; o.w = acc[mt][dt][3] * rl;
      *(float4*)(values_f + qrow * 1024 + d0) = o;
      ushort4 ob;
      ob.x = f2b(o.x); ob.y = f2b(o.y); ob.z = f2b(o.z); ob.w = f2b(o.w);
      *(ushort4*)(values_b + qrow * 1024 + d0) = ob;
    }
  }
}

extern "C" void kernel_launch(void* const* d_in, const int* in_sizes, int n_in,
                              void* d_out, int out_size, void* d_ws, size_t ws_size,
                              hipStream_t stream) {
  const float* x    = (const float*)d_in[0];
  const float* mask = (const float*)d_in[1];
  const float* Wqkv = (const float*)d_in[2];
  const float* bqkv = (const float*)d_in[3];
  const float* Wo   = (const float*)d_in[4];
  const float* bo   = (const float*)d_in[5];
  float* out      = (float*)d_out;
  float* values_f = out + 8388608;

  char* ws = (char*)d_ws;
  ushort* xb    = (ushort*)(ws + 0);          // 16 MB  [8192,1024] bf16
  ushort* wqkvt = (ushort*)(ws + 16777216);   // 6 MB   [3072,1024] bf16 (W_qkv^T)
  ushort* wot   = (ushort*)(ws + 23068672);   // 2 MB   [1024,1024] bf16 (W_o^T)
  ushort* qkv   = (ushort*)(ws + 25165824);   // 48 MB  [8192,3072] bf16
  ushort* valb  = (ushort*)(ws + 75497472);   // 16 MB  [8192,1024] bf16
  unsigned char* mflg = (unsigned char*)(ws + 92274688);  // 256 B mask flags

  prep_all<<<dim3(9472), dim3(256), 0, stream>>>(x, xb, mask, mflg,
                                                 Wqkv, wqkvt, Wo, wot);
  gemm_bt_bias<0, 1><<<dim3(24, 64), dim3(256), 0, stream>>>(
      xb, wqkvt, bqkv, (void*)qkv, 8192, 3072, 1024);
  flash_attn<<<dim3(1024), dim3(256), 0, stream>>>(qkv, mask, mflg, values_f, valb);
  gemm_bt_bias<1, 0><<<dim3(8, 64), dim3(256), 0, stream>>>(
      valb, wot, bo, (void*)out, 8192, 1024, 1024);
}